// Round 1
// baseline (615.447 us; speedup 1.0000x reference)
//
#include <hip/hip_runtime.h>

#define H 64
#define W 64
#define NPIX 4096          // 64*64
#define GH 240
#define GW 240
#define CB 512             // total channels in data
#define CX 256             // x channels

// Block: 256 threads = 64 pixels (8x8 tile) x 4 tps-taps.
// Grid:  8 batches x 64 tiles x 4 channel-groups = 2048 blocks.
__global__ __launch_bounds__(256, 4)
void warp_resblock_fused(const float* __restrict__ data, float* __restrict__ out) {
    const int tid  = threadIdx.x;
    const int bidx = blockIdx.x;
    const int b    = bidx & 7;           // batch -> XCD locality heuristic
    const int rest = bidx >> 3;
    const int cg   = rest & 3;           // channel group (64 channels each)
    const int tile = rest >> 2;          // 0..63
    const int ty = tile >> 3, tx = tile & 7;

    const int p = tid >> 2;              // pixel within 8x8 tile
    const int t = tid & 3;               // tps tap id
    const int oy = ty * 8 + (p >> 3);
    const int ox = tx * 8 + (p & 7);

    const float*  xbase = data + ((size_t)b * CB) * NPIX;                  // channels 0..255
    const float2* gaff  = (const float2*)(data + ((size_t)b * CB + 256) * NPIX);
    const float2* gtps  = (const float2*)(data + ((size_t)b * CB + 384) * NPIX);

    // ---------- Phase A: per-thread stencil (16 taps) ----------
    int   sidx[16];
    float swgt[16];

    // identity-grid resize coords into the 240x240 image (align_corners=True)
    const float fy  = ((float)oy / 63.0f) * 239.0f;
    const float fx  = ((float)ox / 63.0f) * 239.0f;
    const float fy0 = floorf(fy), fx0 = floorf(fx);
    const float wy1 = fy - fy0,  wx1 = fx - fx0;

    const int tty = t >> 1, ttx = t & 1;
    const float gyf = fy0 + (float)tty;
    const float gxf = fx0 + (float)ttx;
    float wt = (tty ? wy1 : 1.0f - wy1) * (ttx ? wx1 : 1.0f - wx1);
    if (gyf < 0.0f || gyf > 239.0f || gxf < 0.0f || gxf > 239.0f) wt = 0.0f;
    const int gyi = min(max((int)gyf, 0), GH - 1);
    const int gxi = min(max((int)gxf, 0), GW - 1);

    // tps grid value at this integer point -> position in warped_aff (240x240)
    const float2 gt = gtps[gyi * GW + gxi];
    const float sx  = (gt.x + 1.0f) * 0.5f * 239.0f;
    const float sy  = (gt.y + 1.0f) * 0.5f * 239.0f;
    const float sy0 = floorf(sy), sx0 = floorf(sx);
    const float wsy1 = sy - sy0,  wsx1 = sx - sx0;

#pragma unroll
    for (int s = 0; s < 4; ++s) {
        const int ssy = s >> 1, ssx = s & 1;
        const float ayf = sy0 + (float)ssy;
        const float axf = sx0 + (float)ssx;
        float ws = (ssy ? wsy1 : 1.0f - wsy1) * (ssx ? wsx1 : 1.0f - wsx1);
        if (ayf < 0.0f || ayf > 239.0f || axf < 0.0f || axf > 239.0f) ws = 0.0f;
        const int ayi = min(max((int)ayf, 0), GH - 1);
        const int axi = min(max((int)axf, 0), GW - 1);

        // aff grid value -> position in x (64x64)
        const float2 ga = gaff[ayi * GW + axi];
        const float qx  = (ga.x + 1.0f) * 0.5f * 63.0f;
        const float qy  = (ga.y + 1.0f) * 0.5f * 63.0f;
        const float qy0 = floorf(qy), qx0 = floorf(qx);
        const float wqy1 = qy - qy0,  wqx1 = qx - qx0;

#pragma unroll
        for (int r = 0; r < 4; ++r) {
            const int rry = r >> 1, rrx = r & 1;
            const float byf = qy0 + (float)rry;
            const float bxf = qx0 + (float)rrx;
            float wr = (rry ? wqy1 : 1.0f - wqy1) * (rrx ? wqx1 : 1.0f - wqx1);
            if (byf < 0.0f || byf > 63.0f || bxf < 0.0f || bxf > 63.0f) wr = 0.0f;
            const int byi = min(max((int)byf, 0), H - 1);
            const int bxi = min(max((int)bxf, 0), W - 1);
            sidx[s * 4 + r] = byi * W + bxi;
            swgt[s * 4 + r] = wt * ws * wr;
        }
    }

    // ---------- Phase B: loop 64 channels, LDS-staged gathers ----------
    __shared__ float ximg[NPIX];
    const int copix = oy * W + ox;
    const int c0 = cg * 64;

    float4 pre[4];
    {
        const float4* src = (const float4*)(xbase + (size_t)c0 * NPIX);
#pragma unroll
        for (int i = 0; i < 4; ++i) pre[i] = src[i * 256 + tid];
    }

    for (int cl = 0; cl < 64; ++cl) {
#pragma unroll
        for (int i = 0; i < 4; ++i) ((float4*)ximg)[i * 256 + tid] = pre[i];
        __syncthreads();

        if (cl < 63) {
            const float4* src = (const float4*)(xbase + (size_t)(c0 + cl + 1) * NPIX);
#pragma unroll
            for (int i = 0; i < 4; ++i) pre[i] = src[i * 256 + tid];
        }

        float acc = 0.0f;
#pragma unroll
        for (int k = 0; k < 16; ++k) acc = fmaf(swgt[k], ximg[sidx[k]], acc);

        acc += __shfl_xor(acc, 1);
        acc += __shfl_xor(acc, 2);

        if (t == 0) {
            out[((size_t)b * CX + (c0 + cl)) * NPIX + copix] = ximg[copix] + acc;
        }
        __syncthreads();
    }
}

extern "C" void kernel_launch(void* const* d_in, const int* in_sizes, int n_in,
                              void* d_out, int out_size, void* d_ws, size_t ws_size,
                              hipStream_t stream) {
    (void)in_sizes; (void)n_in; (void)d_ws; (void)ws_size; (void)out_size;
    const float* data = (const float*)d_in[0];
    float* out = (float*)d_out;
    dim3 grid(2048), block(256);
    hipLaunchKernelGGL(warp_resblock_fused, grid, block, 0, stream, data, out);
}

// Round 2
// 67.459 us; speedup vs baseline: 9.1233x; 9.1233x over previous
//
#include <hip/hip_runtime.h>

#define H 64
#define W 64
#define NPIX 4096          // 64*64
#define GHH 240
#define GWW 240
#define CB 512             // total channels in data
#define CX 256             // x channels

// Grid: 8 batches x 32 channel-groups (8 ch each) = 256 blocks, 1024 threads.
// Each block: stage 8 channels (128 KB LDS, channel-interleaved), then each
// thread computes 4 full output pixels (64-tap fused stencil) for all 8 ch.
__global__ __launch_bounds__(1024, 4)
void warp_resblock_fused(const float* __restrict__ data, float* __restrict__ out) {
    const int tid = threadIdx.x;
    const int b   = blockIdx.x & 7;    // batch -> XCD pinning (round-robin dispatch)
    const int cg  = blockIdx.x >> 3;   // 0..31
    const int c0  = cg * 8;

    const float*  xbase = data + (size_t)b * CB * NPIX;
    const float2* gaff  = (const float2*)(xbase + (size_t)256 * NPIX);
    const float2* gtps  = (const float2*)(xbase + (size_t)384 * NPIX);

    // channel-interleaved staging: xa[pix] = {c0..c0+3}, xb[pix] = {c0+4..c0+7}
    __shared__ float4 xa[NPIX];   // 64 KB
    __shared__ float4 xb[NPIX];   // 64 KB

    {
        const float4* xs = (const float4*)(xbase + (size_t)c0 * NPIX);
        float4 va[4], vb[4];
#pragma unroll
        for (int cc = 0; cc < 4; ++cc) va[cc] = xs[(size_t)cc * 1024 + tid];
#pragma unroll
        for (int cc = 0; cc < 4; ++cc) vb[cc] = xs[(size_t)(4 + cc) * 1024 + tid];
#pragma unroll
        for (int k = 0; k < 4; ++k) {
            const int pix = tid * 4 + k;
            xa[pix] = make_float4(((const float*)&va[0])[k], ((const float*)&va[1])[k],
                                  ((const float*)&va[2])[k], ((const float*)&va[3])[k]);
            xb[pix] = make_float4(((const float*)&vb[0])[k], ((const float*)&vb[1])[k],
                                  ((const float*)&vb[2])[k], ((const float*)&vb[3])[k]);
        }
    }
    __syncthreads();

    for (int pg = 0; pg < 4; ++pg) {
        const int pix = pg * 1024 + tid;
        const int oy = pix >> 6, ox = pix & 63;

        float a0 = 0.f, a1 = 0.f, a2 = 0.f, a3 = 0.f;
        float a4 = 0.f, a5 = 0.f, a6 = 0.f, a7 = 0.f;

        // identity-grid resize coords into the 240x240 image (align_corners=True)
        const float fy  = ((float)oy / 63.0f) * 239.0f;
        const float fx  = ((float)ox / 63.0f) * 239.0f;
        const float fy0 = floorf(fy), fx0 = floorf(fx);
        const float wy1 = fy - fy0,  wx1 = fx - fx0;

#pragma unroll
        for (int t = 0; t < 4; ++t) {
            const int tty = t >> 1, ttx = t & 1;
            const float gyf = fy0 + (float)tty;
            const float gxf = fx0 + (float)ttx;
            float wt = (tty ? wy1 : 1.0f - wy1) * (ttx ? wx1 : 1.0f - wx1);
            if (gyf < 0.0f || gyf > 239.0f || gxf < 0.0f || gxf > 239.0f) wt = 0.0f;
            const int gyi = min(max((int)gyf, 0), GHH - 1);
            const int gxi = min(max((int)gxf, 0), GWW - 1);

            // tps grid value -> position in warped_aff (240x240)
            const float2 gt = gtps[gyi * GWW + gxi];
            const float sx  = (gt.x + 1.0f) * 0.5f * 239.0f;
            const float sy  = (gt.y + 1.0f) * 0.5f * 239.0f;
            const float sy0 = floorf(sy), sx0 = floorf(sx);
            const float wsy1 = sy - sy0,  wsx1 = sx - sx0;

#pragma unroll
            for (int s = 0; s < 4; ++s) {
                const int ssy = s >> 1, ssx = s & 1;
                const float ayf = sy0 + (float)ssy;
                const float axf = sx0 + (float)ssx;
                float ws = (ssy ? wsy1 : 1.0f - wsy1) * (ssx ? wsx1 : 1.0f - wsx1);
                if (ayf < 0.0f || ayf > 239.0f || axf < 0.0f || axf > 239.0f) ws = 0.0f;
                ws *= wt;
                const int ayi = min(max((int)ayf, 0), GHH - 1);
                const int axi = min(max((int)axf, 0), GWW - 1);

                // aff grid value -> position in x (64x64)
                const float2 ga = gaff[ayi * GWW + axi];
                const float qx  = (ga.x + 1.0f) * 0.5f * 63.0f;
                const float qy  = (ga.y + 1.0f) * 0.5f * 63.0f;
                const float qy0 = floorf(qy), qx0 = floorf(qx);
                const float wqy1 = qy - qy0,  wqx1 = qx - qx0;

#pragma unroll
                for (int r = 0; r < 4; ++r) {
                    const int rry = r >> 1, rrx = r & 1;
                    const float byf = qy0 + (float)rry;
                    const float bxf = qx0 + (float)rrx;
                    float wr = (rry ? wqy1 : 1.0f - wqy1) * (rrx ? wqx1 : 1.0f - wqx1);
                    if (byf < 0.0f || byf > 63.0f || bxf < 0.0f || bxf > 63.0f) wr = 0.0f;
                    wr *= ws;
                    const int byi = min(max((int)byf, 0), H - 1);
                    const int bxi = min(max((int)bxf, 0), W - 1);
                    const int idx = byi * W + bxi;
                    const float4 pa = xa[idx];
                    const float4 pb = xb[idx];
                    a0 = fmaf(wr, pa.x, a0); a1 = fmaf(wr, pa.y, a1);
                    a2 = fmaf(wr, pa.z, a2); a3 = fmaf(wr, pa.w, a3);
                    a4 = fmaf(wr, pb.x, a4); a5 = fmaf(wr, pb.y, a5);
                    a6 = fmaf(wr, pb.z, a6); a7 = fmaf(wr, pb.w, a7);
                }
            }
        }

        // residual add + fully coalesced stores (per channel: 4 KB dense)
        const float4 ra = xa[pix];
        const float4 rb = xb[pix];
        float* o = out + ((size_t)b * CX + c0) * NPIX + pix;
        o[0 * NPIX] = ra.x + a0; o[1 * NPIX] = ra.y + a1;
        o[2 * NPIX] = ra.z + a2; o[3 * NPIX] = ra.w + a3;
        o[4 * NPIX] = rb.x + a4; o[5 * NPIX] = rb.y + a5;
        o[6 * NPIX] = rb.z + a6; o[7 * NPIX] = rb.w + a7;
    }
}

extern "C" void kernel_launch(void* const* d_in, const int* in_sizes, int n_in,
                              void* d_out, int out_size, void* d_ws, size_t ws_size,
                              hipStream_t stream) {
    (void)in_sizes; (void)n_in; (void)d_ws; (void)ws_size; (void)out_size;
    const float* data = (const float*)d_in[0];
    float* out = (float*)d_out;
    dim3 grid(256), block(1024);
    hipLaunchKernelGGL(warp_resblock_fused, grid, block, 0, stream, data, out);
}